// Round 4
// baseline (124.436 us; speedup 1.0000x reference)
//
#include <hip/hip_runtime.h>
#include <hip/hip_bf16.h>

// Segment-mean over N=2,000,000 sorted nodes -> G=16384 graphs, then linear.
// x: [N,64] f32, segment_ids: [N] int32 (sorted), weight: [128,64] f32,
// bias: [128] f32, out: [G,128] f32.  HBM-bound: ~520 MB read -> ~84 us floor.
//
// R4 structure: equal-rows phase A (atomic partial-sum accumulation, perfectly
// balanced, all waves resident) + tiny phase B (mean + linear). No binary
// search, no per-graph imbalance, no cold dependent-load startup.

#define IN_CH 64
#define OUT_CH 128
#define RPW 256              // rows per wave in phase A (multiple of 4)
#define ABLK 256             // phase A block: 4 waves
#define BBLK 512             // phase B block: 8 waves
#define BGRID 512            // phase B grid (each wave loops over 4 graphs)

typedef float f32x4 __attribute__((ext_vector_type(4)));

// Wave-uniform flush of the current run's partial sum into global accumulators.
__device__ __forceinline__ void flush_seg(float* __restrict__ sums,
                                          int* __restrict__ counts,
                                          int g, int l, int cq,
                                          f32x4& acc, int& ccnt) {
    float ax = acc.x, ay = acc.y, az = acc.z, aw = acc.w;
    ax += __shfl_xor(ax, 16); ay += __shfl_xor(ay, 16);
    az += __shfl_xor(az, 16); aw += __shfl_xor(aw, 16);
    ax += __shfl_xor(ax, 32); ay += __shfl_xor(ay, 32);
    az += __shfl_xor(az, 32); aw += __shfl_xor(aw, 32);
    int tot = ccnt;
    tot += __shfl_xor(tot, 16);
    tot += __shfl_xor(tot, 32);
    if (l < 16) {
        float* p = sums + (size_t)g * IN_CH + cq;
        atomicAdd(p + 0, ax);
        atomicAdd(p + 1, ay);
        atomicAdd(p + 2, az);
        atomicAdd(p + 3, aw);
    }
    if (l == 0) atomicAdd(counts + g, tot);
    acc.x = 0.f; acc.y = 0.f; acc.z = 0.f; acc.w = 0.f;
    ccnt = 0;
}

// Phase A: each wave streams exactly RPW rows (perfect balance). Lane layout:
// rs = row stream 0..3, cq = channel quad. Fast path: whole 4-row quad belongs
// to the current graph (no cross-lane work). Transitions (~16K total) take the
// uniform slow path: per-stream predicated accumulate with flush between runs.
__global__ __launch_bounds__(ABLK) void seg_accum_kernel(
        const float* __restrict__ x, const int* __restrict__ ids,
        float* __restrict__ sums, int* __restrict__ counts, int N) {
    const int t = threadIdx.x;
    const int w = blockIdx.x * (ABLK / 64) + (t >> 6);
    const int l = t & 63;
    const int row0 = w * RPW;
    if (row0 >= N) return;
    int row_end = row0 + RPW;
    if (row_end > N) row_end = N;          // N,RPW multiples of 4 -> quads intact

    const int rs = l >> 4;
    const int cq = (l & 15) << 2;

    f32x4 acc; acc.x = 0.f; acc.y = 0.f; acc.z = 0.f; acc.w = 0.f;
    int ccnt = 0;
    int cur_g = ids[row0];                 // uniform broadcast load

    for (int r = row0; r < row_end; r += 4) {
        const int id = ids[r + rs];        // 4 distinct addrs, 16-lane broadcast
        const f32x4 v = __builtin_nontemporal_load(
            reinterpret_cast<const f32x4*>(x + (size_t)(r + rs) * IN_CH + cq));
        if (__all(id == cur_g)) {
            acc.x += v.x; acc.y += v.y; acc.z += v.z; acc.w += v.w;
            ++ccnt;
        } else {
            // ids are sorted -> streams' ids non-decreasing; process in order.
            #pragma unroll
            for (int k = 0; k < 4; ++k) {
                const int gk = __shfl(id, k * 16);   // uniform
                if (gk != cur_g) {                    // uniform branch
                    flush_seg(sums, counts, cur_g, l, cq, acc, ccnt);
                    cur_g = gk;
                }
                if (rs == k) {                        // only stream k adds
                    acc.x += v.x; acc.y += v.y; acc.z += v.z; acc.w += v.w;
                    ++ccnt;
                }
            }
        }
    }
    flush_seg(sums, counts, cur_g, l, cq, acc, ccnt);
}

// Phase B: mean + linear. One wave per graph iteration; W tile shared in LDS.
__global__ __launch_bounds__(BBLK) void mean_linear_kernel(
        const float* __restrict__ sums, const int* __restrict__ counts,
        const float* __restrict__ W, const float* __restrict__ bias,
        float* __restrict__ out, int G) {
    __shared__ float w_lds[IN_CH * 129];   // w_lds[c*129+o] = W[o][c]
    const int t = threadIdx.x;
    for (int i = t; i < OUT_CH * IN_CH; i += BBLK) {
        const int o = i >> 6, c = i & 63;
        w_lds[c * 129 + o] = W[i];
    }
    __syncthreads();

    const int wv = t >> 6, l = t & 63;
    const int cq = (l & 15) << 2;
    const float b0 = bias[l], b1 = bias[l + 64];

    for (int g = blockIdx.x * (BBLK / 64) + wv; g < G; g += BGRID * (BBLK / 64)) {
        const float cnt = (float)counts[g];
        const f32x4 s = *reinterpret_cast<const f32x4*>(
            sums + (size_t)g * IN_CH + cq);
        const float m0 = s.x / cnt, m1 = s.y / cnt;
        const float m2 = s.z / cnt, m3 = s.w / cnt;

        float o0 = b0, o1 = b1;
        #pragma unroll
        for (int c = 0; c < IN_CH; ++c) {
            float m;
            switch (c & 3) {
                case 0:  m = __shfl(m0, c >> 2); break;
                case 1:  m = __shfl(m1, c >> 2); break;
                case 2:  m = __shfl(m2, c >> 2); break;
                default: m = __shfl(m3, c >> 2); break;
            }
            o0 = fmaf(w_lds[c * 129 + l],      m, o0);
            o1 = fmaf(w_lds[c * 129 + l + 64], m, o1);
        }
        out[(size_t)g * OUT_CH + l]      = o0;
        out[(size_t)g * OUT_CH + l + 64] = o1;
    }
}

// ---- Fallback (R3 fused kernel) if ws_size is too small for the sums buffer.
#define WPB 8
#define BLOCK (WPB * 64)
__global__ __launch_bounds__(BLOCK) void fused_pool_linear_kernel(
        const float* __restrict__ x, const int* __restrict__ ids,
        const float* __restrict__ W, const float* __restrict__ bias,
        float* __restrict__ out, int N, int G) {
    __shared__ float w_lds[IN_CH * 129];
    const int t  = threadIdx.x;
    const int wv = t >> 6;
    const int l  = t & 63;
    const int g  = blockIdx.x * WPB + wv;

    int s0 = 0, s1 = 0;
    if (g < G) {
        const int target = g + (l & 1);
        int lo = 0, hi = N;
        const int guess = (int)(((long long)target * (long long)N) / (long long)G);
        int wlo = guess - 4096; if (wlo < 0) wlo = 0;
        int whi = guess + 4096; if (whi > N) whi = N;
        const bool ok_lo = (wlo == 0) || (ids[wlo - 1] < target);
        const bool ok_hi = (whi == N) || (ids[whi] >= target);
        if (ok_lo && ok_hi) { lo = wlo; hi = whi; }
        while (lo < hi) {
            const int mid = (lo + hi) >> 1;
            if (ids[mid] < target) lo = mid + 1; else hi = mid;
        }
        s0 = __shfl(lo, 0);
        s1 = __shfl(lo, 1);
    }
    for (int i = t; i < OUT_CH * IN_CH; i += BLOCK) {
        const int o = i >> 6, c = i & 63;
        w_lds[c * 129 + o] = W[i];
    }
    __syncthreads();
    if (g >= G) return;

    const int rs = l >> 4;
    const int cq = (l & 15) << 2;
    float4 a0 = make_float4(0.f, 0.f, 0.f, 0.f);
    float4 a1 = make_float4(0.f, 0.f, 0.f, 0.f);
    int r = s0;
    for (; r + 8 <= s1; r += 8) {
        const f32x4 v0 = __builtin_nontemporal_load(
            reinterpret_cast<const f32x4*>(x + (size_t)(r + rs) * IN_CH + cq));
        const f32x4 v1 = __builtin_nontemporal_load(
            reinterpret_cast<const f32x4*>(x + (size_t)(r + 4 + rs) * IN_CH + cq));
        a0.x += v0.x; a0.y += v0.y; a0.z += v0.z; a0.w += v0.w;
        a1.x += v1.x; a1.y += v1.y; a1.z += v1.z; a1.w += v1.w;
    }
    if (r + 4 <= s1) {
        const f32x4 v = __builtin_nontemporal_load(
            reinterpret_cast<const f32x4*>(x + (size_t)(r + rs) * IN_CH + cq));
        a0.x += v.x; a0.y += v.y; a0.z += v.z; a0.w += v.w;
        r += 4;
    }
    if (r + rs < s1) {
        const f32x4 v = __builtin_nontemporal_load(
            reinterpret_cast<const f32x4*>(x + (size_t)(r + rs) * IN_CH + cq));
        a1.x += v.x; a1.y += v.y; a1.z += v.z; a1.w += v.w;
    }
    float sx = a0.x + a1.x, sy = a0.y + a1.y;
    float sz = a0.z + a1.z, sw = a0.w + a1.w;
    sx += __shfl_xor(sx, 16); sy += __shfl_xor(sy, 16);
    sz += __shfl_xor(sz, 16); sw += __shfl_xor(sw, 16);
    sx += __shfl_xor(sx, 32); sy += __shfl_xor(sy, 32);
    sz += __shfl_xor(sz, 32); sw += __shfl_xor(sw, 32);
    const float cnt = (float)(s1 - s0);
    const float m0 = sx / cnt, m1 = sy / cnt, m2 = sz / cnt, m3 = sw / cnt;
    float o0 = bias[l], o1 = bias[l + 64];
    #pragma unroll
    for (int c = 0; c < IN_CH; ++c) {
        float m;
        switch (c & 3) {
            case 0:  m = __shfl(m0, c >> 2); break;
            case 1:  m = __shfl(m1, c >> 2); break;
            case 2:  m = __shfl(m2, c >> 2); break;
            default: m = __shfl(m3, c >> 2); break;
        }
        o0 = fmaf(w_lds[c * 129 + l],      m, o0);
        o1 = fmaf(w_lds[c * 129 + l + 64], m, o1);
    }
    out[(size_t)g * OUT_CH + l]      = o0;
    out[(size_t)g * OUT_CH + l + 64] = o1;
}

extern "C" void kernel_launch(void* const* d_in, const int* in_sizes, int n_in,
                              void* d_out, int out_size, void* d_ws, size_t ws_size,
                              hipStream_t stream) {
    const float* x    = (const float*)d_in[0];
    const int*   ids  = (const int*)d_in[1];
    const float* W    = (const float*)d_in[2];
    const float* bias = (const float*)d_in[3];
    float* out = (float*)d_out;

    const int N = in_sizes[1];             // 2,000,000
    const int G = out_size / OUT_CH;       // 16384

    const size_t sums_bytes = (size_t)G * IN_CH * sizeof(float);
    const size_t need = sums_bytes + (size_t)G * sizeof(int);

    if (ws_size >= need) {
        float* sums   = (float*)d_ws;
        int*   counts = (int*)((char*)d_ws + sums_bytes);
        hipMemsetAsync(d_ws, 0, need, stream);
        const int waves   = (N + RPW - 1) / RPW;
        const int ablocks = (waves + (ABLK / 64) - 1) / (ABLK / 64);
        seg_accum_kernel<<<ablocks, ABLK, 0, stream>>>(x, ids, sums, counts, N);
        mean_linear_kernel<<<BGRID, BBLK, 0, stream>>>(sums, counts, W, bias, out, G);
    } else {
        const int blocks = (G + WPB - 1) / WPB;
        fused_pool_linear_kernel<<<blocks, BLOCK, 0, stream>>>(
            x, ids, W, bias, out, N, G);
    }
}

// Round 5
// 118.959 us; speedup vs baseline: 1.0460x; 1.0460x over previous
//
#include <hip/hip_runtime.h>
#include <hip/hip_bf16.h>

// Segment-mean over N=2,000,000 sorted nodes -> G=16384 graphs, then linear.
// x: [N,64] f32, segment_ids: [N] int32 (sorted), weight: [128,64] f32,
// bias: [128] f32, out: [G,128] f32.  HBM-bound: ~520 MB read -> ~84 us floor.
//
// R5: LDS-free pool kernel (2 graphs/wave, 8192 waves = exactly 32/CU x 256 CU,
// single cohort -> CU-level bandwidth sharing balances the segment-size
// variance) writes means[G][64] to ws; tiny linear kernel does W@mean+b.
// Hot loop is branch-free (R4 lesson: never put id loads in the stream).

#define IN_CH 64
#define OUT_CH 128
#define GPW 2                // graphs per wave
#define PBLK 256             // pool block: 4 waves
#define LBLK 512             // linear block: 8 waves
#define LGRID 512            // linear grid

typedef float f32x4 __attribute__((ext_vector_type(4)));

// Branch-free segment stream: sum rows [s0,s1) of x into per-lane partials,
// butterfly-reduce so every lane ends with the full sum of its channel quad.
__device__ __forceinline__ void stream_seg(const float* __restrict__ x,
                                           int s0, int s1, int rs, int cq,
                                           float& sx, float& sy,
                                           float& sz, float& sw) {
    float4 a0 = make_float4(0.f, 0.f, 0.f, 0.f);
    float4 a1 = make_float4(0.f, 0.f, 0.f, 0.f);
    int r = s0;
    for (; r + 8 <= s1; r += 8) {
        const f32x4 v0 = __builtin_nontemporal_load(
            reinterpret_cast<const f32x4*>(x + (size_t)(r + rs) * IN_CH + cq));
        const f32x4 v1 = __builtin_nontemporal_load(
            reinterpret_cast<const f32x4*>(x + (size_t)(r + 4 + rs) * IN_CH + cq));
        a0.x += v0.x; a0.y += v0.y; a0.z += v0.z; a0.w += v0.w;
        a1.x += v1.x; a1.y += v1.y; a1.z += v1.z; a1.w += v1.w;
    }
    if (r + 4 <= s1) {
        const f32x4 v = __builtin_nontemporal_load(
            reinterpret_cast<const f32x4*>(x + (size_t)(r + rs) * IN_CH + cq));
        a0.x += v.x; a0.y += v.y; a0.z += v.z; a0.w += v.w;
        r += 4;
    }
    if (r + rs < s1) {
        const f32x4 v = __builtin_nontemporal_load(
            reinterpret_cast<const f32x4*>(x + (size_t)(r + rs) * IN_CH + cq));
        a1.x += v.x; a1.y += v.y; a1.z += v.z; a1.w += v.w;
    }
    sx = a0.x + a1.x; sy = a0.y + a1.y;
    sz = a0.z + a1.z; sw = a0.w + a1.w;
    sx += __shfl_xor(sx, 16); sy += __shfl_xor(sy, 16);
    sz += __shfl_xor(sz, 16); sw += __shfl_xor(sw, 16);
    sx += __shfl_xor(sx, 32); sy += __shfl_xor(sy, 32);
    sz += __shfl_xor(sz, 32); sw += __shfl_xor(sw, 32);
}

// Pool kernel: no LDS, no atomics. Wave w owns graphs 2w, 2w+1; finds the 3
// boundaries via windowed binary search (validated window, full-range
// fallback -> correct for any sorted input), streams both segments
// back-to-back, writes means[g][0:64].
__global__ __launch_bounds__(PBLK, 8) void pool_kernel(
        const float* __restrict__ x, const int* __restrict__ ids,
        float* __restrict__ means, int N, int G) {
    const int t  = threadIdx.x;
    const int w  = blockIdx.x * (PBLK / 64) + (t >> 6);
    const int l  = t & 63;
    const int g0 = w * GPW;
    if (g0 >= G) return;

    // Lanes 0,1,2 search lower_bound for g0, g0+1, g0+2 (lanes >=2 duplicate
    // target g0+2 -> each probe touches only 3 distinct addresses).
    const int tgt = g0 + ((l < 2) ? l : 2);
    int lo = 0, hi = N;
    {
        const int guess = (int)(((long long)tgt * (long long)N) / (long long)G);
        int wlo = guess - 4096; if (wlo < 0) wlo = 0;
        int whi = guess + 4096; if (whi > N) whi = N;
        const bool ok_lo = (wlo == 0) || (ids[wlo - 1] < tgt);
        const bool ok_hi = (whi == N) || (ids[whi] >= tgt);
        if (ok_lo && ok_hi) { lo = wlo; hi = whi; }
        while (lo < hi) {
            const int mid = (lo + hi) >> 1;
            if (ids[mid] < tgt) lo = mid + 1; else hi = mid;
        }
    }
    const int s0 = __shfl(lo, 0);
    const int s1 = __shfl(lo, 1);
    const int s2 = __shfl(lo, 2);

    const int rs = l >> 4;              // row stream 0..3
    const int cq = (l & 15) << 2;       // channel quad base

    float sx, sy, sz, sw;

    stream_seg(x, s0, s1, rs, cq, sx, sy, sz, sw);
    {
        const float cnt = (float)(s1 - s0);
        if (l < 16) {
            f32x4 m; m.x = sx / cnt; m.y = sy / cnt; m.z = sz / cnt; m.w = sw / cnt;
            *reinterpret_cast<f32x4*>(means + (size_t)g0 * IN_CH + cq) = m;
        }
    }

    if (g0 + 1 < G) {
        stream_seg(x, s1, s2, rs, cq, sx, sy, sz, sw);
        const float cnt = (float)(s2 - s1);
        if (l < 16) {
            f32x4 m; m.x = sx / cnt; m.y = sy / cnt; m.z = sz / cnt; m.w = sw / cnt;
            *reinterpret_cast<f32x4*>(means + (size_t)(g0 + 1) * IN_CH + cq) = m;
        }
    }
}

// Linear kernel: out[g] = W @ mean[g] + b.  W transposed in LDS (stride 129).
__global__ __launch_bounds__(LBLK) void linear_kernel(
        const float* __restrict__ means, const float* __restrict__ W,
        const float* __restrict__ bias, float* __restrict__ out, int G) {
    __shared__ float w_lds[IN_CH * 129];   // w_lds[c*129+o] = W[o][c]
    const int t = threadIdx.x;
    for (int i = t; i < OUT_CH * IN_CH; i += LBLK) {
        const int o = i >> 6, c = i & 63;
        w_lds[c * 129 + o] = W[i];
    }
    __syncthreads();

    const int wv = t >> 6, l = t & 63;
    const int cq = (l & 15) << 2;
    const float b0 = bias[l], b1 = bias[l + 64];

    for (int g = blockIdx.x * (LBLK / 64) + wv; g < G; g += LGRID * (LBLK / 64)) {
        const f32x4 s = *reinterpret_cast<const f32x4*>(
            means + (size_t)g * IN_CH + cq);
        const float m0 = s.x, m1 = s.y, m2 = s.z, m3 = s.w;

        float o0 = b0, o1 = b1;
        #pragma unroll
        for (int c = 0; c < IN_CH; ++c) {
            float m;
            switch (c & 3) {
                case 0:  m = __shfl(m0, c >> 2); break;
                case 1:  m = __shfl(m1, c >> 2); break;
                case 2:  m = __shfl(m2, c >> 2); break;
                default: m = __shfl(m3, c >> 2); break;
            }
            o0 = fmaf(w_lds[c * 129 + l],      m, o0);
            o1 = fmaf(w_lds[c * 129 + l + 64], m, o1);
        }
        out[(size_t)g * OUT_CH + l]      = o0;
        out[(size_t)g * OUT_CH + l + 64] = o1;
    }
}

// ---- Fallback (R3 fused kernel) if ws is too small for means.
#define WPB 8
#define BLOCK (WPB * 64)
__global__ __launch_bounds__(BLOCK) void fused_pool_linear_kernel(
        const float* __restrict__ x, const int* __restrict__ ids,
        const float* __restrict__ W, const float* __restrict__ bias,
        float* __restrict__ out, int N, int G) {
    __shared__ float w_lds[IN_CH * 129];
    const int t  = threadIdx.x;
    const int wv = t >> 6;
    const int l  = t & 63;
    const int g  = blockIdx.x * WPB + wv;

    int s0 = 0, s1 = 0;
    if (g < G) {
        const int target = g + (l & 1);
        int lo = 0, hi = N;
        const int guess = (int)(((long long)target * (long long)N) / (long long)G);
        int wlo = guess - 4096; if (wlo < 0) wlo = 0;
        int whi = guess + 4096; if (whi > N) whi = N;
        const bool ok_lo = (wlo == 0) || (ids[wlo - 1] < target);
        const bool ok_hi = (whi == N) || (ids[whi] >= target);
        if (ok_lo && ok_hi) { lo = wlo; hi = whi; }
        while (lo < hi) {
            const int mid = (lo + hi) >> 1;
            if (ids[mid] < target) lo = mid + 1; else hi = mid;
        }
        s0 = __shfl(lo, 0);
        s1 = __shfl(lo, 1);
    }
    for (int i = t; i < OUT_CH * IN_CH; i += BLOCK) {
        const int o = i >> 6, c = i & 63;
        w_lds[c * 129 + o] = W[i];
    }
    __syncthreads();
    if (g >= G) return;

    const int rs = l >> 4;
    const int cq = (l & 15) << 2;
    float sx, sy, sz, sw;
    stream_seg(x, s0, s1, rs, cq, sx, sy, sz, sw);
    const float cnt = (float)(s1 - s0);
    const float m0 = sx / cnt, m1 = sy / cnt, m2 = sz / cnt, m3 = sw / cnt;
    float o0 = bias[l], o1 = bias[l + 64];
    #pragma unroll
    for (int c = 0; c < IN_CH; ++c) {
        float m;
        switch (c & 3) {
            case 0:  m = __shfl(m0, c >> 2); break;
            case 1:  m = __shfl(m1, c >> 2); break;
            case 2:  m = __shfl(m2, c >> 2); break;
            default: m = __shfl(m3, c >> 2); break;
        }
        o0 = fmaf(w_lds[c * 129 + l],      m, o0);
        o1 = fmaf(w_lds[c * 129 + l + 64], m, o1);
    }
    out[(size_t)g * OUT_CH + l]      = o0;
    out[(size_t)g * OUT_CH + l + 64] = o1;
}

extern "C" void kernel_launch(void* const* d_in, const int* in_sizes, int n_in,
                              void* d_out, int out_size, void* d_ws, size_t ws_size,
                              hipStream_t stream) {
    const float* x    = (const float*)d_in[0];
    const int*   ids  = (const int*)d_in[1];
    const float* W    = (const float*)d_in[2];
    const float* bias = (const float*)d_in[3];
    float* out = (float*)d_out;

    const int N = in_sizes[1];             // 2,000,000
    const int G = out_size / OUT_CH;       // 16384

    const size_t means_bytes = (size_t)G * IN_CH * sizeof(float);

    if (ws_size >= means_bytes) {
        float* means = (float*)d_ws;
        const int waves   = (G + GPW - 1) / GPW;                    // 8192
        const int pblocks = (waves + (PBLK / 64) - 1) / (PBLK / 64); // 2048
        pool_kernel<<<pblocks, PBLK, 0, stream>>>(x, ids, means, N, G);
        linear_kernel<<<LGRID, LBLK, 0, stream>>>(means, W, bias, out, G);
    } else {
        const int blocks = (G + WPB - 1) / WPB;
        fused_pool_linear_kernel<<<blocks, BLOCK, 0, stream>>>(
            x, ids, W, bias, out, N, G);
    }
}